// Round 21
// baseline (459.183 us; speedup 1.0000x reference)
//
#include <hip/hip_runtime.h>

#define NN     6000
#define KNN    15
#define EPB    32          // edges per node = 2*(KNN+1)
#define HID    512
#define NLAYER 3
#define OUTDIM 12000       // NN * MODES
#define MB     128         // edge rows per block (4 nodes)
#define NTH    512         // 8 waves; wave tile 128 rows x 64 cols (32x32 frags)
#define NKT    16          // k-tiles per layer (K=512 / 32)
#define NG     (NLAYER * NKT)   // 48 k-tiles total

typedef _Float16 half8   __attribute__((ext_vector_type(8)));
typedef _Float16 half4v  __attribute__((ext_vector_type(4)));
typedef float    floatx4 __attribute__((ext_vector_type(4)));
typedef float    floatx16 __attribute__((ext_vector_type(16)));

// ---------- one-time: Wh fp32 [l][k][n] -> 32x32x16 MFMA-A-tiled f16 ----------
// Wt = [l][kt=16][ks2=2][nt=16] x 1KB blocks; lane ln holds
// half8 { W[kt*32 + ks2*16 + (ln>>5)*8 + j][nt*32 + (ln&31)], j=0..7 }.
__global__ void prep_weights(const float* __restrict__ Wh, _Float16* __restrict__ Wt)
{
    const int blk = blockIdx.x;          // ((l*16+kt)*2+ks2)*16 + nt, 0..1535
    const int ln  = threadIdx.x;         // 0..63
    const int nt  = blk & 15;
    const int ks2 = (blk >> 4) & 1;
    const int kt  = (blk >> 5) & 15;
    const int l   = blk >> 9;
    const int k0  = kt * 32 + ks2 * 16 + (ln >> 5) * 8;
    const int n   = nt * 32 + (ln & 31);
    const float* src = Wh + (size_t)l * HID * HID + (size_t)k0 * HID + n;
    half8 v;
#pragma unroll
    for (int j = 0; j < 8; ++j) v[j] = (_Float16)src[(size_t)j * HID];
    *(half8*)(Wt + (size_t)blk * 512 + ln * 8) = v;
}

// ---------- fused MLP (32x32x16 MFMA) + in-kernel zeroing + band write ----------
// Block m owns output rows [8m, 8m+8). Wave w: rows 0..127 x cols [w*64,+64).
// LDS (dynamic): Ah [128][512] f16 XOR-swizzled = 131072 B.
__global__ __launch_bounds__(NTH, 1)
void mlp_mfma_kernel(const float* __restrict__ CK,     // [NN, EPB, 3]
                     const float* __restrict__ W_in,   // [3, HID] fp32
                     const float* __restrict__ b_in,   // [HID]
                     const float* __restrict__ bh,     // [NLAYER, HID]
                     const float* __restrict__ W_out,  // [HID, 4] fp32
                     const float* __restrict__ b_out,  // [4]
                     const _Float16* __restrict__ Wt,  // tiled weights
                     float* __restrict__ out)          // [OUTDIM*OUTDIM]
{
    extern __shared__ float4 smem4[];
    _Float16* Ah = (_Float16*)smem4;                   // 131072 B
    __shared__ float  xs[MB * 3];
    __shared__ float4 edgeval[MB];
    __shared__ float  bandv[4][2][80];

    const int t  = threadIdx.x;
    const int w  = t >> 6;          // wave 0..7 -> cols [w*64, w*64+64)
    const int ln = t & 63;
    const int l5 = ln & 31;         // 32x32 frag row/col index
    const int kg = ln >> 5;         // k-group 0/1 (8 halves each)
    const int swzA = (ln & 7) << 3; // row-keyed: (row&7)==(ln&7) for 32-aligned rf
    const int m  = blockIdx.x;      // 0..1499

    // zero one owned output row (band window skipped), nt full-line stores
    const floatx4 z4 = (floatx4){0.f, 0.f, 0.f, 0.f};
#define ZROW(Q) do {                                                           \
        const int n_   = 4 * m + ((Q) >> 1);                                   \
        const int cmin_ = (n_ - KNN < 0) ? 0 : n_ - KNN;                       \
        const int cmax_ = (n_ + KNN + 1 > NN - 1) ? NN - 1 : n_ + KNN + 1;     \
        const int end_  = 2 * cmin_ + 2 * (cmax_ - cmin_ + 1);                 \
        const int wlo_  = (2 * cmin_) & ~3;                                    \
        const int whi_  = (end_ + 3) & ~3;                                     \
        float* rowp_ = out + (size_t)(8 * m + (Q)) * OUTDIM;                   \
        for (int i_ = t; i_ < OUTDIM / 4; i_ += NTH) {                         \
            const int j_ = 4 * i_;                                             \
            if (j_ < wlo_ || j_ >= whi_)                                       \
                __builtin_nontemporal_store(z4, (floatx4*)(rowp_ + j_));       \
        }                                                                      \
    } while (0)

    // B frag (g, ks2, cfi) at half8-offset (g*32 + ks2*16 + 2w + cfi)*64 + ln
    const half8* __restrict__ Wt8 = (const half8*)Wt + ln;
    const int wb = 2 * w;

    // ---- issue B tiles 0,1 immediately (fly during input layer) ----
    half8 bA[4], bB[4];
#pragma unroll
    for (int k2 = 0; k2 < 2; ++k2)
#pragma unroll
        for (int c = 0; c < 2; ++c) {
            bA[k2 * 2 + c] = Wt8[(size_t)(0 * 32 + k2 * 16 + wb + c) * 64];
            bB[k2 * 2 + c] = Wt8[(size_t)(1 * 32 + k2 * 16 + wb + c) * 64];
        }

    // ---- stage inputs (4 nodes = 384 floats) ----
    if (t < MB * 3) xs[t] = CK[(size_t)m * (MB * 3) + t];
    __syncthreads();

    // ---- input layer (fp32 VALU): one column per thread, 128 rows ----
    {
        const int j0 = t;
        const float wi0 = W_in[j0], wi1 = W_in[HID + j0], wi2 = W_in[2 * HID + j0];
        const float bi  = b_in[j0];
#pragma unroll 8
        for (int r = 0; r < MB; ++r) {
            float a = fmaf(xs[r * 3 + 2], wi2,
                      fmaf(xs[r * 3 + 1], wi1,
                      fmaf(xs[r * 3 + 0], wi0, bi)));
            Ah[r * HID + (j0 ^ ((r & 7) << 3))] = (_Float16)fmaxf(a, 0.f);
        }
    }
    __syncthreads();

    // One k-tile (K=32 = 2 ksteps of 16): per kstep load 4 A-frags, 8 MFMA.
    // Refill RCUR <- tile G+2 (depth-2 counted vmcnt).
#define KSTEP(G, RCUR) do {                                                    \
        const int kt_ = ((G) & 15) * 32;                                       \
        _Pragma("unroll")                                                      \
        for (int k2_ = 0; k2_ < 2; ++k2_) {                                    \
            half8 a_[4];                                                       \
            const int kb_ = kt_ + k2_ * 16 + kg * 8;                           \
            _Pragma("unroll")                                                  \
            for (int rf_ = 0; rf_ < 4; ++rf_)                                  \
                a_[rf_] = *(const half8*)                                      \
                    &Ah[(rf_ * 32 + l5) * HID + (kb_ ^ swzA)];                 \
            __builtin_amdgcn_s_setprio(1);                                     \
            _Pragma("unroll")                                                  \
            for (int rf_ = 0; rf_ < 4; ++rf_)                                  \
                _Pragma("unroll")                                              \
                for (int cf_ = 0; cf_ < 2; ++cf_)                              \
                    acc[rf_][cf_] = __builtin_amdgcn_mfma_f32_32x32x16_f16(    \
                        RCUR[k2_ * 2 + cf_], a_[rf_], acc[rf_][cf_], 0, 0, 0); \
            __builtin_amdgcn_s_setprio(0);                                     \
        }                                                                      \
        if ((G) + 2 < NG) {                                                    \
            _Pragma("unroll")                                                  \
            for (int k2_ = 0; k2_ < 2; ++k2_)                                  \
                _Pragma("unroll")                                              \
                for (int c_ = 0; c_ < 2; ++c_)                                 \
                    RCUR[k2_ * 2 + c_] = Wt8[(size_t)(((G) + 2) * 32           \
                                             + k2_ * 16 + wb + c_) * 64];      \
        }                                                                      \
    } while (0)

    // ---- hidden layers: barrier-free k-loop, zero stores overlapped ----
    for (int layer = 0; layer < NLAYER; ++layer) {
        const float* __restrict__ bias = bh + layer * HID;

        // C^T: lane holds r = rf*32+l5; n = w*64+cf*32+(reg&3)+8*(reg>>2)+4*kg
        floatx16 acc[4][2];
#pragma unroll
        for (int cf = 0; cf < 2; ++cf) {
            floatx16 bv;
#pragma unroll
            for (int reg = 0; reg < 16; ++reg)
                bv[reg] = bias[w * 64 + cf * 32 + (reg & 3) + 8 * (reg >> 2) + 4 * kg];
#pragma unroll
            for (int rf = 0; rf < 4; ++rf) acc[rf][cf] = bv;
        }

        // zeros: 3/3/2 rows per layer, drain under the k-loop
        ZROW(layer * 3);
        ZROW(layer * 3 + 1);
        if (layer < 2) ZROW(layer * 3 + 2);

#pragma unroll
        for (int kt2 = 0; kt2 < NKT; kt2 += 2) {
            const int g = layer * NKT + kt2;
            KSTEP(g,     bA);
            KSTEP(g + 1, bB);
        }

        __syncthreads();   // all waves done reading Ah this layer
        // ---- writeback: relu(C^T frag) -> Ah, b64 per reg-quad ----
#pragma unroll
        for (int rf = 0; rf < 4; ++rf) {
            const int r = rf * 32 + l5;
#pragma unroll
            for (int cf = 0; cf < 2; ++cf) {
#pragma unroll
                for (int g4 = 0; g4 < 4; ++g4) {
                    const int ng = w * 64 + cf * 32 + 8 * g4 + 4 * kg;
                    half4v h4;
#pragma unroll
                    for (int i = 0; i < 4; ++i)
                        h4[i] = (_Float16)fmaxf(acc[rf][cf][g4 * 4 + i], 0.f);
                    *(half4v*)&Ah[r * HID + (ng ^ swzA)] = h4;
                }
            }
        }
        __syncthreads();   // new Ah visible
    }

    // ---- output layer (512 -> 4) -> edgeval in LDS ----
    {
        const int s = t & 7;
        const float4 bo = *(const float4*)b_out;
#pragma unroll
        for (int pass = 0; pass < 2; ++pass) {
            const int rr = pass * 64 + (t >> 3);   // 0..127
            const int swzr = (rr & 7) << 3;
            float p0 = 0.f, p1 = 0.f, p2 = 0.f, p3 = 0.f;
            for (int i = 0; i < HID / 8; ++i) {
                const int k = s + i * 8;
                const float hv = (float)Ah[rr * HID + (k ^ swzr)];
                const floatx4 wv = *(const floatx4*)&W_out[k * 4];
                p0 = fmaf(hv, wv[0], p0);
                p1 = fmaf(hv, wv[1], p1);
                p2 = fmaf(hv, wv[2], p2);
                p3 = fmaf(hv, wv[3], p3);
            }
#pragma unroll
            for (int mm = 1; mm < 8; mm <<= 1) {
                p0 += __shfl_xor(p0, mm, 64);
                p1 += __shfl_xor(p1, mm, 64);
                p2 += __shfl_xor(p2, mm, 64);
                p3 += __shfl_xor(p3, mm, 64);
            }
            if (s == 0)
                edgeval[rr] = make_float4(p0 + bo.x, p1 + bo.y, p2 + bo.z, p3 + bo.w);
        }
    }
    __syncthreads();

    // ---- band composition (deterministic, in-block) ----
    if (t < 128) {
        const int nd = t >> 5, ci = t & 31;
        const int n  = 4 * m + nd;
        const int cmin  = (n - KNN < 0) ? 0 : n - KNN;
        const int cmax  = (n + KNN + 1 > NN - 1) ? NN - 1 : n + KNN + 1;
        const int width = cmax - cmin + 1;
        if (ci < width) {
            const int c = cmin + ci;
            int e_lo, e_hi;
            if (c == 0)           { e_lo = 0;                  e_hi = KNN - n; }
            else if (c == NN - 1) { e_lo = (NN - 1) - n + KNN; e_hi = EPB - 1; }
            else                  { e_lo = e_hi = c - n + KNN; }
            float s0 = 0.f, s1 = 0.f, s2 = 0.f, s3 = 0.f;
            for (int e = e_lo; e <= e_hi; ++e) {
                const float4 pv = edgeval[nd * EPB + e];
                s0 += pv.x; s1 += pv.y; s2 += pv.z; s3 += pv.w;
            }
            bandv[nd][0][2 * ci] = s0; bandv[nd][0][2 * ci + 1] = s1;
            bandv[nd][1][2 * ci] = s2; bandv[nd][1][2 * ci + 1] = s3;
        }
    }
    __syncthreads();

    // ---- write the 8 band windows (16B-aligned; zeros outside band) ----
#pragma unroll
    for (int pass = 0; pass < 2; ++pass) {
        if (t < 320) {
            const int q  = pass * 4 + t / 80;   // row 0..7
            const int jl = t % 80;
            const int nd = q >> 1, mi = q & 1;
            const int n  = 4 * m + nd;
            const int cmin  = (n - KNN < 0) ? 0 : n - KNN;
            const int cmax  = (n + KNN + 1 > NN - 1) ? NN - 1 : n + KNN + 1;
            const int end   = 2 * cmin + 2 * (cmax - cmin + 1);
            const int wlo   = (2 * cmin) & ~3;
            const int whi   = (end + 3) & ~3;
            const int j     = wlo + jl;
            if (j < whi) {
                const bool inside = (j >= 2 * cmin) && (j < end);
                const float v = inside ? bandv[nd][mi][j - 2 * cmin] : 0.f;
                out[(size_t)(8 * m + q) * OUTDIM + j] = v;
            }
        }
    }
}

extern "C" void kernel_launch(void* const* d_in, const int* in_sizes, int n_in,
                              void* d_out, int out_size, void* d_ws, size_t ws_size,
                              hipStream_t stream) {
    const float* CK    = (const float*)d_in[0];
    const float* W_in  = (const float*)d_in[1];
    const float* b_in  = (const float*)d_in[2];
    const float* Wh    = (const float*)d_in[3];
    const float* bh    = (const float*)d_in[4];
    const float* W_out = (const float*)d_in[5];
    const float* b_out = (const float*)d_in[6];
    float* out = (float*)d_out;

    _Float16* Wt = (_Float16*)d_ws;    // 1.5 MB tiled weights

    (void)ws_size;
    hipFuncSetAttribute((const void*)mlp_mfma_kernel,
                        hipFuncAttributeMaxDynamicSharedMemorySize, 131072);

    prep_weights<<<NLAYER * 16 * 2 * 16, 64, 0, stream>>>(Wh, Wt);
    mlp_mfma_kernel<<<NN / 4, NTH, 131072, stream>>>(CK, W_in, b_in, bh,
                                                     W_out, b_out, Wt, out);
}

// Round 22
// 384.298 us; speedup vs baseline: 1.1949x; 1.1949x over previous
//
#include <hip/hip_runtime.h>

#define NN     6000
#define KNN    15
#define EPB    32          // edges per node = 2*(KNN+1)
#define HID    512
#define NLAYER 3
#define OUTDIM 12000       // NN * MODES
#define MB     96          // edge rows per block (3 nodes)
#define NTH    512         // 8 waves
#define NKT    16          // k-tiles per layer (K=512 / 32)
#define NG     (NLAYER * NKT)   // 48 k-tiles total

typedef _Float16 half8  __attribute__((ext_vector_type(8)));
typedef _Float16 half4v __attribute__((ext_vector_type(4)));
typedef float    floatx4 __attribute__((ext_vector_type(4)));

// LDS-only barrier: orders LDS ops across the workgroup WITHOUT draining
// outstanding global (nt zero-store / prefetch) traffic. Safe here because
// the only cross-wave data at these points is Ah/edgeval/bandv (LDS), and
// the nt stores' target region is disjoint from every later access.
#define LDS_BARRIER() do {                                   \
        asm volatile("s_waitcnt lgkmcnt(0)" ::: "memory");   \
        __builtin_amdgcn_s_barrier();                        \
        __builtin_amdgcn_sched_barrier(0);                   \
    } while (0)

// ---------- one-time: Wh fp32 [l][k][n] -> MFMA-fragment-tiled f16 ----------
// Wt = [l][kt=16][nt=32] x 1KB blocks; lane ln holds
// half8 { W[kt*32 + (ln>>4)*8 + j][nt*16 + (ln&15)] , j=0..7 }.
__global__ void prep_weights(const float* __restrict__ Wh, _Float16* __restrict__ Wt)
{
    const int blk = blockIdx.x;          // ((l*16)+kt)*32 + nt
    const int ln  = threadIdx.x;         // 0..63
    const int nt  = blk & 31;
    const int kt  = (blk >> 5) & 15;
    const int l   = blk >> 9;
    const int lc  = ln & 15, lg = ln >> 4;
    const float* src = Wh + (size_t)l * HID * HID
                          + (size_t)(kt * 32 + lg * 8) * HID + nt * 16 + lc;
    half8 v;
#pragma unroll
    for (int j = 0; j < 8; ++j) v[j] = (_Float16)src[(size_t)j * HID];
    *(half8*)(Wt + (size_t)blk * 512 + ln * 8) = v;
}

// ---------- fused MLP + in-kernel zeroing + direct band write ----------
// Block m owns output rows [6m, 6m+6) exclusively.
// LDS (dynamic): Ah [96][512] f16 XOR-swizzled = 98304 B.
__global__ __launch_bounds__(NTH, 1)
void mlp_mfma_kernel(const float* __restrict__ CK,     // [NN, EPB, 3]
                     const float* __restrict__ W_in,   // [3, HID] fp32
                     const float* __restrict__ b_in,   // [HID]
                     const float* __restrict__ bh,     // [NLAYER, HID]
                     const float* __restrict__ W_out,  // [HID, 4] fp32
                     const float* __restrict__ b_out,  // [4]
                     const _Float16* __restrict__ Wt,  // tiled weights
                     float* __restrict__ out)          // [OUTDIM*OUTDIM]
{
    extern __shared__ float4 smem4[];
    _Float16* Ah = (_Float16*)smem4;                   // 98304 B
    __shared__ float  xs[MB * 3];
    __shared__ float4 edgeval[MB];                     // per-edge MLP outputs
    __shared__ float  bandv[3][2][80];                 // per-node band values

    const int t  = threadIdx.x;
    const int w  = t >> 6;          // wave 0..7 -> cols [w*64, w*64+64)
    const int ln = t & 63;
    const int lc = ln & 15;
    const int lg = ln >> 4;         // 0..3
    const int kbase = lg * 8;
    const int swzA  = (lc & 7) << 3;
    const int m  = blockIdx.x;      // 0..1999

    // zero one owned output row (band window skipped), nt full-line stores
    const floatx4 z4 = (floatx4){0.f, 0.f, 0.f, 0.f};
#define ZROW(Q) do {                                                           \
        const int n_   = 3 * m + ((Q) >> 1);                                   \
        const int cmin_ = (n_ - KNN < 0) ? 0 : n_ - KNN;                       \
        const int cmax_ = (n_ + KNN + 1 > NN - 1) ? NN - 1 : n_ + KNN + 1;     \
        const int end_  = 2 * cmin_ + 2 * (cmax_ - cmin_ + 1);                 \
        const int wlo_  = (2 * cmin_) & ~3;                                    \
        const int whi_  = (end_ + 3) & ~3;                                     \
        float* rowp_ = out + (size_t)(6 * m + (Q)) * OUTDIM;                   \
        for (int i_ = t; i_ < OUTDIM / 4; i_ += NTH) {                         \
            const int j_ = 4 * i_;                                             \
            if (j_ < wlo_ || j_ >= whi_)                                       \
                __builtin_nontemporal_store(z4, (floatx4*)(rowp_ + j_));       \
        }                                                                      \
    } while (0)

    // wave's B base (half8 units): tile g at g*2048; frag nf at (w*4+nf)*64 + ln
    const half8* __restrict__ Wt8 = (const half8*)Wt + (size_t)(w * 4) * 64 + ln;

    // ---- issue B tiles 0,1 immediately (fly during input layer) ----
    half8 bA[4], bB[4];
#pragma unroll
    for (int nf = 0; nf < 4; ++nf) bA[nf] = Wt8[(size_t)0 * 2048 + nf * 64];
#pragma unroll
    for (int nf = 0; nf < 4; ++nf) bB[nf] = Wt8[(size_t)1 * 2048 + nf * 64];

    // ---- stage inputs (3 nodes = 288 floats) ----
    if (t < MB * 3) xs[t] = CK[(size_t)m * (MB * 3) + t];
    __syncthreads();

    // ---- input layer (fp32 VALU): one column per thread, 96 rows ----
    {
        const int j0 = t;
        const float wi0 = W_in[j0], wi1 = W_in[HID + j0], wi2 = W_in[2 * HID + j0];
        const float bi  = b_in[j0];
#pragma unroll 8
        for (int r = 0; r < MB; ++r) {
            float a = fmaf(xs[r * 3 + 2], wi2,
                      fmaf(xs[r * 3 + 1], wi1,
                      fmaf(xs[r * 3 + 0], wi0, bi)));
            Ah[r * HID + (j0 ^ ((r & 7) << 3))] = (_Float16)fmaxf(a, 0.f);
        }
    }
    LDS_BARRIER();

    // One k-tile: A-frags from LDS, 24 MFMA from RCUR, refill RCUR <- tile G+2.
#define KSTEP(G, RCUR) do {                                                    \
        half8 a_[6];                                                           \
        const int kb_ = ((G) & 15) * 32 + kbase;                               \
        _Pragma("unroll")                                                      \
        for (int mf_ = 0; mf_ < 6; ++mf_)                                      \
            a_[mf_] = *(const half8*)&Ah[(mf_ * 16 + lc) * HID + (kb_ ^ swzA)];\
        __builtin_amdgcn_s_setprio(1);                                         \
        _Pragma("unroll")                                                      \
        for (int mf_ = 0; mf_ < 6; ++mf_)                                      \
            _Pragma("unroll")                                                  \
            for (int nf_ = 0; nf_ < 4; ++nf_)                                  \
                acc[mf_][nf_] = __builtin_amdgcn_mfma_f32_16x16x32_f16(        \
                    RCUR[nf_], a_[mf_], acc[mf_][nf_], 0, 0, 0);               \
        __builtin_amdgcn_s_setprio(0);                                         \
        if ((G) + 2 < NG) {                                                    \
            _Pragma("unroll")                                                  \
            for (int nf_ = 0; nf_ < 4; ++nf_)                                  \
                RCUR[nf_] = Wt8[(size_t)((G) + 2) * 2048 + nf_ * 64];          \
        }                                                                      \
    } while (0)

    // ---- hidden layers: barrier-free k-loop, zero stores overlapped ----
    for (int layer = 0; layer < NLAYER; ++layer) {
        const float* __restrict__ bias = bh + layer * HID;

        floatx4 acc[6][4];   // operand-swapped: lane holds r=mf*16+lc, n=w*64+nf*16+lg*4+j
#pragma unroll
        for (int nf = 0; nf < 4; ++nf) {
            const floatx4 bv = *(const floatx4*)&bias[w * 64 + nf * 16 + lg * 4];
#pragma unroll
            for (int mf = 0; mf < 6; ++mf) acc[mf][nf] = bv;
        }

        // issue 2 rows of zeros; they drain lazily (no barrier ever waits on them)
        ZROW(layer * 2);
        ZROW(layer * 2 + 1);

#pragma unroll
        for (int kt2 = 0; kt2 < NKT; kt2 += 2) {
            const int g = layer * NKT + kt2;
            KSTEP(g,     bA);
            KSTEP(g + 1, bB);
        }

        LDS_BARRIER();     // all waves done reading Ah (LDS order only)
        // ---- writeback: relu(C^T frag) -> Ah, b64 per frag ----
#pragma unroll
        for (int mf = 0; mf < 6; ++mf) {
            const int r = mf * 16 + lc;
#pragma unroll
            for (int nf = 0; nf < 4; ++nf) {
                const int n0 = w * 64 + nf * 16 + lg * 4;
                half4v h4;
#pragma unroll
                for (int j = 0; j < 4; ++j)
                    h4[j] = (_Float16)fmaxf(acc[mf][nf][j], 0.f);
                *(half4v*)&Ah[r * HID + (n0 ^ swzA)] = h4;
            }
        }
        LDS_BARRIER();     // new Ah visible
    }

    // ---- output layer (512 -> 4) -> edgeval in LDS ----
    {
        const int s = t & 7;
        const float4 bo = *(const float4*)b_out;
#pragma unroll
        for (int pass = 0; pass < 2; ++pass) {
            const int rr = pass * 64 + (t >> 3);
            if (rr < MB) {
                const int swzr = (rr & 7) << 3;
                float p0 = 0.f, p1 = 0.f, p2 = 0.f, p3 = 0.f;
                for (int i = 0; i < HID / 8; ++i) {
                    const int k = s + i * 8;
                    const float hv = (float)Ah[rr * HID + (k ^ swzr)];
                    const floatx4 wv = *(const floatx4*)&W_out[k * 4];
                    p0 = fmaf(hv, wv[0], p0);
                    p1 = fmaf(hv, wv[1], p1);
                    p2 = fmaf(hv, wv[2], p2);
                    p3 = fmaf(hv, wv[3], p3);
                }
#pragma unroll
                for (int mm = 1; mm < 8; mm <<= 1) {
                    p0 += __shfl_xor(p0, mm, 64);
                    p1 += __shfl_xor(p1, mm, 64);
                    p2 += __shfl_xor(p2, mm, 64);
                    p3 += __shfl_xor(p3, mm, 64);
                }
                if (s == 0)
                    edgeval[rr] = make_float4(p0 + bo.x, p1 + bo.y,
                                              p2 + bo.z, p3 + bo.w);
            }
        }
    }
    LDS_BARRIER();

    // ---- band composition (deterministic, in-block) ----
    if (t < 96) {
        const int nd = t >> 5, ci = t & 31;
        const int n  = 3 * m + nd;
        const int cmin  = (n - KNN < 0) ? 0 : n - KNN;
        const int cmax  = (n + KNN + 1 > NN - 1) ? NN - 1 : n + KNN + 1;
        const int width = cmax - cmin + 1;
        if (ci < width) {
            const int c = cmin + ci;
            int e_lo, e_hi;
            if (c == 0)           { e_lo = 0;                  e_hi = KNN - n; }
            else if (c == NN - 1) { e_lo = (NN - 1) - n + KNN; e_hi = EPB - 1; }
            else                  { e_lo = e_hi = c - n + KNN; }
            float s0 = 0.f, s1 = 0.f, s2 = 0.f, s3 = 0.f;
            for (int e = e_lo; e <= e_hi; ++e) {
                const float4 pv = edgeval[nd * EPB + e];
                s0 += pv.x; s1 += pv.y; s2 += pv.z; s3 += pv.w;
            }
            bandv[nd][0][2 * ci] = s0; bandv[nd][0][2 * ci + 1] = s1;
            bandv[nd][1][2 * ci] = s2; bandv[nd][1][2 * ci + 1] = s3;
        }
    }
    LDS_BARRIER();

    // ---- write the 6 band windows (16B-aligned; zeros outside band) ----
    if (t < 6 * 80) {
        const int q  = t / 80;          // row 0..5
        const int jl = t % 80;
        const int nd = q >> 1, mi = q & 1;
        const int n  = 3 * m + nd;
        const int cmin  = (n - KNN < 0) ? 0 : n - KNN;
        const int cmax  = (n + KNN + 1 > NN - 1) ? NN - 1 : n + KNN + 1;
        const int end   = 2 * cmin + 2 * (cmax - cmin + 1);
        const int wlo   = (2 * cmin) & ~3;
        const int whi   = (end + 3) & ~3;
        const int j     = wlo + jl;
        if (j < whi) {
            const bool inside = (j >= 2 * cmin) && (j < end);
            const float v = inside ? bandv[nd][mi][j - 2 * cmin] : 0.f;
            out[(size_t)(6 * m + q) * OUTDIM + j] = v;
        }
    }
}

extern "C" void kernel_launch(void* const* d_in, const int* in_sizes, int n_in,
                              void* d_out, int out_size, void* d_ws, size_t ws_size,
                              hipStream_t stream) {
    const float* CK    = (const float*)d_in[0];
    const float* W_in  = (const float*)d_in[1];
    const float* b_in  = (const float*)d_in[2];
    const float* Wh    = (const float*)d_in[3];
    const float* bh    = (const float*)d_in[4];
    const float* W_out = (const float*)d_in[5];
    const float* b_out = (const float*)d_in[6];
    float* out = (float*)d_out;

    _Float16* Wt = (_Float16*)d_ws;    // 1.5 MB tiled weights

    (void)ws_size;
    hipFuncSetAttribute((const void*)mlp_mfma_kernel,
                        hipFuncAttributeMaxDynamicSharedMemorySize, 98304);

    prep_weights<<<NLAYER * 16 * 32, 64, 0, stream>>>(Wh, Wt);
    mlp_mfma_kernel<<<NN / 3, NTH, 98304, stream>>>(CK, W_in, b_in, bh,
                                                    W_out, b_out, Wt, out);
}